// Round 2
// baseline (104.382 us; speedup 1.0000x reference)
//
#include <hip/hip_runtime.h>
#include <hip/hip_bf16.h>
#include <stdint.h>

typedef __bf16 bf16x8 __attribute__((ext_vector_type(8)));
typedef float  f32x4  __attribute__((ext_vector_type(4)));

#define CIN   64
#define COUT  128
#define HH    128
#define WW    128
#define BB    8

#define TROW  130                       // y' rows per batch (halo rows 0,129 zero)
#define TCOL  130                       // x' pixels per row (halo cols 0,129 zero)
#define ROWBYTES (TCOL * CIN * 2)       // 16640 B per (b,y') row
#define TSIZE ((size_t)BB * TROW * ROWBYTES)  // 17,305,600 B

// Swizzled byte offset inside one T row: x'*128 + (((c>>3) ^ (x'&7))<<4) + (c&7)*2
// The same function is used by the writer (transpose_pass) and the reader
// (depthcnn_main K-loop); global_load_lds copies rows linearly so the LDS
// image equals the T image (guideline 21: linear dest + pre-swizzled source).

// ---------------- pass 0: weights into MFMA-B fragment order (bf16) ------------
// Bprep[((n*18 + s)*64 + lane)*8 + j] = W2[o][c*9+k],
//   o = n*16 + (lane&15); c = (s&1)*32 + ((lane>>4)&3)*8 + j; k = s>>1
__global__ void prep_weights(const float* __restrict__ wflat, __bf16* __restrict__ bp) {
    int idx = blockIdx.x * 256 + threadIdx.x;
    if (idx >= 8 * 18 * 64 * 8) return;
    int j = idx & 7;
    int l = (idx >> 3) & 63;
    int s = (idx >> 9) % 18;
    int n = idx / (18 * 512);
    int o = n * 16 + (l & 15);
    int c = ((s & 1) << 5) + ((l >> 4) << 3) + j;
    int k = s >> 1;
    bp[idx] = (__bf16)wflat[o * 576 + c * 9 + k];
}

// ---------------- pass 1: input (B,C,H,W) f32 -> T[b][y'][x'][c] bf16, swizzled --
__global__ __launch_bounds__(256) void transpose_pass(const float* __restrict__ inp,
                                                      __bf16* __restrict__ T) {
    __shared__ float sT[64][129];   // +1 pad: conflict-free strided reads
    const int b   = blockIdx.x >> 7;
    const int y   = blockIdx.x & 127;
    const int tid = threadIdx.x;

    // load 64c x 128x f32 for this (b,y), coalesced: lanes 0-31 cover one c-row
    const float* ib = inp + ((long)b * CIN * HH + y) * WW;
    const int xq = tid & 31, c8 = tid >> 5;
    #pragma unroll
    for (int i = 0; i < 8; ++i) {
        int c = c8 * 8 + i;
        float4 v = *(const float4*)(ib + (long)c * (HH * WW) + (xq << 2));
        *(float4*)&sT[c][xq << 2] = v;
    }
    __syncthreads();

    // write c-innermost bf16 with the 16B-slot XOR swizzle baked in
    const int x  = tid & 127;
    const int ch = tid >> 7;                  // 0..1
    char* rowp = (char*)T + (size_t)(b * TROW + y + 1) * ROWBYTES + (size_t)(x + 1) * 128;
    const int sw = (x + 1) & 7;
    for (int c0 = ch * 8; c0 < 64; c0 += 16) {
        bf16x8 v;
        #pragma unroll
        for (int j = 0; j < 8; ++j) v[j] = (__bf16)sT[c0 + j][x];
        *(bf16x8*)(rowp + ((((c0 >> 3) ^ sw)) << 4)) = v;
    }
}

// ---------------- pass 2: main — one block per (b, y) output row ----------------
__global__ __launch_bounds__(256, 3) void depthcnn_main(
    const __bf16* __restrict__ T, const float* __restrict__ gbuf,
    const float* __restrict__ bias, const __bf16* __restrict__ bprep,
    float* __restrict__ out)
{
    __shared__ __align__(1024) char sInB[3 * ROWBYTES];  // 49920 B, linear copy of 3 T rows
    __shared__ float sWf[9][WW];                         // 4608 B  -> total 54528: 3 blk/CU

    const int b    = blockIdx.x >> 7;
    const int y    = blockIdx.x & 127;
    const int tid  = threadIdx.x;
    const int wave = tid >> 6;
    const int lane = tid & 63;

    // ---- stage: 3 contiguous T rows (y..y+2 == input rows y-1..y+1), linear DMA
    {
        const char* src = (const char*)T + (size_t)(b * TROW + y) * ROWBYTES;
        #pragma unroll
        for (int t = wave; t < 49; t += 4) {            // 3120 16B-chunks total
            if ((t << 6) + lane < 3120) {
                __builtin_amdgcn_global_load_lds(
                    (const __attribute__((address_space(1))) uint32_t*)(src + ((size_t)t << 10) + (lane << 4)),
                    (__attribute__((address_space(3))) uint32_t*)(sInB + (t << 10)),
                    16, 0, 0);
            }
        }
    }
    // ---- bilateral weights wf[9][x] (OOB depth = 0 enters denominator)
    if (tid < WW) {
        const float* g = gbuf + ((long)b * 2 + 1) * (HH * WW);
        const int x = tid;
        float dc = 2.f * (g[y * WW + x] - 0.5f);
        float e[9];
        float ssum = 0.f;
        #pragma unroll
        for (int k = 0; k < 9; ++k) {
            int yy = y + (k / 3) - 1;
            int xx = x + (k % 3) - 1;
            float dn = 0.f;
            if ((unsigned)yy < 128u && (unsigned)xx < 128u)
                dn = 2.f * (g[yy * WW + xx] - 0.5f);
            float df = dn - dc;
            float ek = __expf(-df * df);
            e[k] = ek;
            ssum += ek;
        }
        float sc = 9.f / ssum;
        #pragma unroll
        for (int k = 0; k < 9; ++k) sWf[k][x] = e[k] * sc;
    }
    __syncthreads();

    const int m16 = lane & 15;    // A row (pixel) within 16
    const int g4  = lane >> 4;    // k-group
    const int x0  = wave << 5;    // 32 pixels per wave

    f32x4 acc[2][8];
    #pragma unroll
    for (int mi = 0; mi < 2; ++mi)
        #pragma unroll
        for (int n = 0; n < 8; ++n)
            acc[mi][n] = (f32x4){0.f, 0.f, 0.f, 0.f};

    const bf16x8* __restrict__ bp = (const bf16x8*)bprep;

    #pragma unroll
    for (int s = 0; s < 18; ++s) {
        const int k  = s >> 1;
        const int dy = k / 3;
        const int dx = k - 3 * dy;
        const int slotbase = ((s & 1) << 2) + g4;       // 16B slot before swizzle
        bf16x8 afr[2];
        #pragma unroll
        for (int mi = 0; mi < 2; ++mi) {
            const int xl = x0 + mi * 16 + m16;          // output x = T x'-1; tap reads x'=xl+dx
            const int px = xl + dx;
            const int off = ((dy * TROW + px) << 7) + ((slotbase ^ (px & 7)) << 4);
            bf16x8 iv = *(const bf16x8*)(sInB + off);   // 16B aligned, ~2-way banks
            float wfv = sWf[k][xl];
            bf16x8 a;
            #pragma unroll
            for (int j = 0; j < 8; ++j) a[j] = (__bf16)((float)iv[j] * wfv);
            afr[mi] = a;
        }
        #pragma unroll
        for (int n = 0; n < 8; ++n) {
            bf16x8 bfr = bp[(n * 18 + s) * 64 + lane];
            acc[0][n] = __builtin_amdgcn_mfma_f32_16x16x32_bf16(afr[0], bfr, acc[0][n], 0, 0, 0);
            acc[1][n] = __builtin_amdgcn_mfma_f32_16x16x32_bf16(afr[1], bfr, acc[1][n], 0, 0, 0);
        }
    }

    // ---- epilogue: D[row=pixel][col=o]; row = g4*4 + r, col = m16
    float* ob = out + ((long)b * COUT * HH + y) * WW;
    #pragma unroll
    for (int n = 0; n < 8; ++n) {
        int o = n * 16 + m16;
        float bv = bias[o];
        #pragma unroll
        for (int mi = 0; mi < 2; ++mi) {
            #pragma unroll
            for (int r = 0; r < 4; ++r) {
                int px = x0 + mi * 16 + g4 * 4 + r;
                ob[(long)o * (HH * WW) + px] = acc[mi][n][r] + bv;
            }
        }
    }
}

extern "C" void kernel_launch(void* const* d_in, const int* in_sizes, int n_in,
                              void* d_out, int out_size, void* d_ws, size_t ws_size,
                              hipStream_t stream) {
    const float* inp  = (const float*)d_in[0];
    const float* gbuf = (const float*)d_in[1];
    const float* wts  = (const float*)d_in[2];
    const float* bias = (const float*)d_in[3];

    __bf16* T  = (__bf16*)d_ws;                          // 17,305,600 B
    __bf16* bp = (__bf16*)((char*)d_ws + TSIZE);         // +147,456 B

    hipMemsetAsync(d_ws, 0, TSIZE, stream);              // zeroes all halo rows/cols
    hipLaunchKernelGGL(transpose_pass, dim3(BB * HH), dim3(256), 0, stream, inp, T);
    hipLaunchKernelGGL(prep_weights, dim3(288), dim3(256), 0, stream, wts, bp);
    hipLaunchKernelGGL(depthcnn_main, dim3(BB * HH), dim3(256), 0, stream,
                       inp ? T : T, gbuf, bias, bp, (float*)d_out);
}

// Round 3
// 56.480 us; speedup vs baseline: 1.8481x; 1.8481x over previous
//
#include <hip/hip_runtime.h>
#include <hip/hip_bf16.h>
#include <stdint.h>

typedef _Float16 f16x8 __attribute__((ext_vector_type(8)));
typedef float    f32x4 __attribute__((ext_vector_type(4)));

#define CIN   64
#define COUT  128
#define HH    128
#define WW    128
#define BB    8

#define TROW  130                         // y' rows per batch (halo rows 0,129 zero)
#define ROWBYTES (130 * 128)              // 16640 B per (b,y') row: 130 x' * 64c * 2B
#define TSIZE ((size_t)BB * TROW * ROWBYTES)   // 17,305,600 B

// T row byte layout (f16, c-innermost, XOR-swizzled 16B slots):
//   byte(x', c) = x'*128 + (((c>>3) ^ (x'&7)) << 4) + (c&7)*2
// Written by transpose_pass, copied linearly to LDS, read with same swizzle.

// ---------------- pass 0: weights -> MFMA-B fragment order (f16) ----------------
// frag[( (nt*18 + s)*64 + lane )*8 + j] = W2[o][c*9+k]
//   o = nt*16 + (lane&15); c = (s&1)*32 + ((lane>>4)&3)*8 + j; k = s>>1
__global__ void prep_weights(const float* __restrict__ wflat, _Float16* __restrict__ bp) {
    int idx = blockIdx.x * 256 + threadIdx.x;
    if (idx >= 8 * 18 * 64 * 8) return;
    int j = idx & 7;
    int l = (idx >> 3) & 63;
    int s = (idx >> 9) % 18;
    int n = idx / (18 * 512);
    int o = n * 16 + (l & 15);
    int c = ((s & 1) << 5) + ((l >> 4) << 3) + j;
    int k = s >> 1;
    bp[idx] = (_Float16)wflat[o * 576 + c * 9 + k];
}

// ---------------- pass 0b: zero halo rows y'=0,129 of each batch -----------------
__global__ void zero_halo(_Float16* __restrict__ T) {
    int idx = blockIdx.x * 256 + threadIdx.x;
    if (idx >= 16 * 1040) return;                     // 16 rows * 1040 16B-chunks
    int row = idx / 1040, c = idx - row * 1040;
    int b = row >> 1, yp = (row & 1) * 129;
    f16x8 z = {};
    *(f16x8*)((char*)T + (size_t)(b * TROW + yp) * ROWBYTES + c * 16) = z;
}

// ---------------- pass 1: input (B,C,H,W) f32 -> T[b][y'][x'][c] f16, swizzled ---
__global__ __launch_bounds__(256) void transpose_pass(const float* __restrict__ inp,
                                                      _Float16* __restrict__ T) {
    __shared__ float sT[64][129];
    const int b   = blockIdx.x >> 7;
    const int y   = blockIdx.x & 127;
    const int tid = threadIdx.x;

    const float* ib = inp + ((long)b * CIN * HH + y) * WW;
    const int xq = tid & 31, c8 = tid >> 5;
    #pragma unroll
    for (int i = 0; i < 8; ++i) {
        int c = c8 * 8 + i;
        float4 v = *(const float4*)(ib + (long)c * (HH * WW) + (xq << 2));
        *(float4*)&sT[c][xq << 2] = v;
    }
    __syncthreads();

    const int x  = tid & 127;
    const int ch = tid >> 7;                  // 0..1
    char* rowp = (char*)T + (size_t)(b * TROW + y + 1) * ROWBYTES + (size_t)(x + 1) * 128;
    const int sw = (x + 1) & 7;
    for (int c0 = ch * 8; c0 < 64; c0 += 16) {
        f16x8 v;
        #pragma unroll
        for (int j = 0; j < 8; ++j) v[j] = (_Float16)sT[c0 + j][x];
        *(f16x8*)(rowp + (((c0 >> 3) ^ sw) << 4)) = v;
    }
    // zero col halos x'=0 and x'=129 of this row
    if (tid < 16) {
        char* basep = (char*)T + (size_t)(b * TROW + y + 1) * ROWBYTES
                    + ((tid >> 3) ? 129 * 128 : 0) + (tid & 7) * 16;
        f16x8 z = {};
        *(f16x8*)basep = z;
    }
}

// ---------------- pass 2: main — one block per (b, y) output row -----------------
// 4 waves: wave(mi,ni) owns 4 m-tiles (64 px) x 4 n-tiles (64 out-ch).
// B fragments register-hoisted in 3 pages of 6 K-steps -> no global loads in loop.
__global__ __launch_bounds__(256, 2) void depthcnn_main(
    const _Float16* __restrict__ T, const float* __restrict__ gbuf,
    const float* __restrict__ bias, const _Float16* __restrict__ bprep,
    float* __restrict__ out)
{
    __shared__ __align__(1024) char sInB[3 * ROWBYTES];  // 49920 B
    __shared__ _Float16 sWfH[9][WW];                     // 2304 B

    const int b   = blockIdx.x >> 7;
    const int y   = blockIdx.x & 127;
    const int tid = threadIdx.x;

    // ---- stage 3 T rows (y', y'+1, y'+2) linearly via async DMA
    {
        const char* src = (const char*)T + (size_t)(b * TROW + y) * ROWBYTES;
        for (int t = tid; t < 3120; t += 256) {          // 3120 16B chunks
            __builtin_amdgcn_global_load_lds(
                (const __attribute__((address_space(1))) uint32_t*)(src + (size_t)t * 16),
                (__attribute__((address_space(3))) uint32_t*)(sInB + t * 16),
                16, 0, 0);
        }
    }
    // ---- bilateral weights wf[9][x] -> f16 (OOB depth = 0 enters denominator)
    if (tid < WW) {
        const float* g = gbuf + ((long)b * 2 + 1) * (HH * WW);
        const int x = tid;
        float dc = 2.f * (g[y * WW + x] - 0.5f);
        float e[9];
        float ssum = 0.f;
        #pragma unroll
        for (int k = 0; k < 9; ++k) {
            int yy = y + (k / 3) - 1;
            int xx = x + (k % 3) - 1;
            float dn = 0.f;
            if ((unsigned)yy < 128u && (unsigned)xx < 128u)
                dn = 2.f * (g[yy * WW + xx] - 0.5f);
            float df = dn - dc;
            float ek = __expf(-df * df);
            e[k] = ek;
            ssum += ek;
        }
        float sc = 9.f / ssum;
        #pragma unroll
        for (int k = 0; k < 9; ++k) sWfH[k][x] = (_Float16)(e[k] * sc);
    }
    __syncthreads();

    const int wave = tid >> 6;
    const int lane = tid & 63;
    const int mi   = wave >> 1;
    const int ni   = wave & 1;
    const int m16  = lane & 15;
    const int g4   = lane >> 4;
    const int mbase = mi * 64;
    const int obase = ni * 64;

    f32x4 acc[4][4];
    #pragma unroll
    for (int m = 0; m < 4; ++m)
        #pragma unroll
        for (int n = 0; n < 4; ++n)
            acc[m][n] = (f32x4){0.f, 0.f, 0.f, 0.f};

    const f16x8* __restrict__ bpv = (const f16x8*)bprep;

    #pragma unroll
    for (int pg = 0; pg < 3; ++pg) {
        // bulk-load this page's 24 B fragments into registers (pipelined)
        f16x8 bfr[4][6];
        #pragma unroll
        for (int n = 0; n < 4; ++n)
            #pragma unroll
            for (int ss = 0; ss < 6; ++ss)
                bfr[n][ss] = bpv[(size_t)(((ni * 4 + n) * 18) + pg * 6 + ss) * 64 + lane];

        #pragma unroll
        for (int ss = 0; ss < 6; ++ss) {
            const int s     = pg * 6 + ss;
            const int k     = s >> 1;
            const int chalf = s & 1;
            const int dy    = k / 3;
            const int dx    = k - 3 * dy;
            const int P0    = mbase + m16 + dx;          // x' for m=0; P0&7 invariant in m
            const int abase = dy * ROWBYTES + P0 * 128
                            + (((chalf << 2) | g4) ^ (P0 & 7)) * 16;
            #pragma unroll
            for (int m = 0; m < 4; ++m) {
                f16x8 iv = *(const f16x8*)(sInB + abase + m * 2048);
                _Float16 wh = sWfH[k][mbase + m * 16 + m16];
                f16x8 w8 = {wh, wh, wh, wh, wh, wh, wh, wh};
                f16x8 av = iv * w8;
                #pragma unroll
                for (int n = 0; n < 4; ++n)
                    acc[m][n] = __builtin_amdgcn_mfma_f32_16x16x32_f16(
                        av, bfr[n][ss], acc[m][n], 0, 0, 0);
            }
        }
    }

    // ---- epilogue: D row = pixel (g4*4+r within tile), col = out-channel (m16)
    float* ob = out + ((long)b * COUT * HH + y) * WW;
    #pragma unroll
    for (int n = 0; n < 4; ++n) {
        const int o = obase + n * 16 + m16;
        const float bv = bias[o];
        #pragma unroll
        for (int m = 0; m < 4; ++m) {
            #pragma unroll
            for (int r = 0; r < 4; ++r) {
                int px = mbase + m * 16 + g4 * 4 + r;
                ob[(long)o * (HH * WW) + px] = acc[m][n][r] + bv;
            }
        }
    }
}

extern "C" void kernel_launch(void* const* d_in, const int* in_sizes, int n_in,
                              void* d_out, int out_size, void* d_ws, size_t ws_size,
                              hipStream_t stream) {
    const float* inp  = (const float*)d_in[0];
    const float* gbuf = (const float*)d_in[1];
    const float* wts  = (const float*)d_in[2];
    const float* bias = (const float*)d_in[3];

    _Float16* T  = (_Float16*)d_ws;                     // 17,305,600 B
    _Float16* bp = (_Float16*)((char*)d_ws + TSIZE);    // +147,456 B

    hipLaunchKernelGGL(zero_halo, dim3(65), dim3(256), 0, stream, T);
    hipLaunchKernelGGL(transpose_pass, dim3(BB * HH), dim3(256), 0, stream, inp, T);
    hipLaunchKernelGGL(prep_weights, dim3(288), dim3(256), 0, stream, wts, bp);
    hipLaunchKernelGGL(depthcnn_main, dim3(BB * HH), dim3(256), 0, stream,
                       T, gbuf, bias, bp, (float*)d_out);
}

// Round 4
// 52.018 us; speedup vs baseline: 2.0067x; 1.0858x over previous
//
#include <hip/hip_runtime.h>
#include <hip/hip_bf16.h>
#include <stdint.h>

typedef _Float16 f16x8 __attribute__((ext_vector_type(8)));
typedef float    f32x4 __attribute__((ext_vector_type(4)));

#define CIN   64
#define COUT  128
#define HH    128
#define WW    128
#define BB    8

#define TROW  130                         // y' rows per batch (halo rows 0,129 zero)
#define ROWBYTES (130 * 128)              // 16640 B per (b,y') row: 130 x' * 64c * 2B
#define TSIZE ((size_t)BB * TROW * ROWBYTES)   // 17,305,600 B

// T row byte layout (f16, c-innermost, XOR-swizzled 16B slots):
//   byte(x', c) = x'*128 + (((c>>3) ^ (x'&7)) << 4) + (c&7)*2

// ---------------- pass 0: weights -> MFMA-A fragment order (f16) ----------------
// A-frag (M=o, K=kk): lane l holds A[l&15][(l>>4)*8+j]
// frag[((nt*18 + s)*64 + lane)*8 + j] = W2[nt*16+(l&15)][c*9+k],
//   c = (s&1)*32 + ((l>>4)&3)*8 + j; k = s>>1   (same formula as before)
__global__ void prep_weights(const float* __restrict__ wflat, _Float16* __restrict__ bp) {
    int idx = blockIdx.x * 256 + threadIdx.x;
    if (idx >= 8 * 18 * 64 * 8) return;
    int j = idx & 7;
    int l = (idx >> 3) & 63;
    int s = (idx >> 9) % 18;
    int n = idx / (18 * 512);
    int o = n * 16 + (l & 15);
    int c = ((s & 1) << 5) + ((l >> 4) << 3) + j;
    int k = s >> 1;
    bp[idx] = (_Float16)wflat[o * 576 + c * 9 + k];
}

// ---------------- pass 0b: zero halo rows y'=0,129 of each batch -----------------
__global__ void zero_halo(_Float16* __restrict__ T) {
    int idx = blockIdx.x * 256 + threadIdx.x;
    if (idx >= 16 * 1040) return;
    int row = idx / 1040, c = idx - row * 1040;
    int b = row >> 1, yp = (row & 1) * 129;
    f16x8 z = {};
    *(f16x8*)((char*)T + (size_t)(b * TROW + yp) * ROWBYTES + c * 16) = z;
}

// ---------------- pass 1: input (B,C,H,W) f32 -> T[b][y'][x'][c] f16, swizzled ---
__global__ __launch_bounds__(256) void transpose_pass(const float* __restrict__ inp,
                                                      _Float16* __restrict__ T) {
    __shared__ float sT[64][129];
    const int b   = blockIdx.x >> 7;
    const int y   = blockIdx.x & 127;
    const int tid = threadIdx.x;

    const float* ib = inp + ((long)b * CIN * HH + y) * WW;
    const int xq = tid & 31, c8 = tid >> 5;
    #pragma unroll
    for (int i = 0; i < 8; ++i) {
        int c = c8 * 8 + i;
        float4 v = *(const float4*)(ib + (long)c * (HH * WW) + (xq << 2));
        *(float4*)&sT[c][xq << 2] = v;
    }
    __syncthreads();

    const int x  = tid & 127;
    const int ch = tid >> 7;
    char* rowp = (char*)T + (size_t)(b * TROW + y + 1) * ROWBYTES + (size_t)(x + 1) * 128;
    const int sw = (x + 1) & 7;
    for (int c0 = ch * 8; c0 < 64; c0 += 16) {
        f16x8 v;
        #pragma unroll
        for (int j = 0; j < 8; ++j) v[j] = (_Float16)sT[c0 + j][x];
        *(f16x8*)(rowp + (((c0 >> 3) ^ sw) << 4)) = v;
    }
    if (tid < 16) {   // zero col halos x'=0, x'=129
        char* basep = (char*)T + (size_t)(b * TROW + y + 1) * ROWBYTES
                    + ((tid >> 3) ? 129 * 128 : 0) + (tid & 7) * 16;
        f16x8 z = {};
        *(f16x8*)basep = z;
    }
}

// ---------------- pass 2: main — one block per (b, 4-row strip) ------------------
// 512 threads = 8 waves; wave (oi,pi): 2 o-tiles (32 ch) x 4 px-tiles (64 px).
// Weights persistent in regs (36 frags); input in 4-slot LDS ring, 1-row prefetch.
__global__ __launch_bounds__(512, 2) void depthcnn_main(
    const _Float16* __restrict__ T, const float* __restrict__ gbuf,
    const float* __restrict__ bias, const _Float16* __restrict__ aprep,
    float* __restrict__ out)
{
    __shared__ __align__(1024) char sIn[4 * ROWBYTES];   // 66,560 B ring, slot = trow&3
    __shared__ _Float16 sWf[4][9][WW];                   // 9,216 B

    const int b      = blockIdx.x >> 5;
    const int ystart = (blockIdx.x & 31) << 2;
    const int tid    = threadIdx.x;
    const int wave   = tid >> 6;
    const int lane   = tid & 63;
    const int oi     = wave >> 1;          // 0..3
    const int pi     = wave & 1;           // 0..1
    const int l15    = lane & 15;
    const int g4     = lane >> 4;
    const int pxbase = pi << 6;

    const char* Tb = (const char*)T + (size_t)b * TROW * ROWBYTES;

    // ---- prologue stage: T rows ystart..ystart+2 into ring slots
    #pragma unroll
    for (int i = 0; i < 3; ++i) {
        const int t = ystart + i;
        const char* src = Tb + (size_t)t * ROWBYTES;
        char* dst = sIn + (t & 3) * ROWBYTES;
        for (int c = tid; c < 1040; c += 512)
            __builtin_amdgcn_global_load_lds(
                (const __attribute__((address_space(1))) uint32_t*)(src + c * 16),
                (__attribute__((address_space(3))) uint32_t*)(dst + c * 16), 16, 0, 0);
    }

    // ---- wf for all 4 rows (128 threads per row)
    {
        const int r = tid >> 7, x = tid & 127, y = ystart + r;
        const float* g = gbuf + ((size_t)b * 2 + 1) * (HH * WW);
        float dc = 2.f * (g[y * WW + x] - 0.5f);
        float e[9];
        float ssum = 0.f;
        #pragma unroll
        for (int k = 0; k < 9; ++k) {
            int yy = y + (k / 3) - 1;
            int xx = x + (k % 3) - 1;
            float dn = 0.f;
            if ((unsigned)yy < 128u && (unsigned)xx < 128u)
                dn = 2.f * (g[yy * WW + xx] - 0.5f);
            float df = dn - dc;
            float ek = __expf(-df * df);
            e[k] = ek;
            ssum += ek;
        }
        float sc = 9.f / ssum;
        #pragma unroll
        for (int k = 0; k < 9; ++k) sWf[r][k][x] = (_Float16)(e[k] * sc);
    }

    // ---- persistent weight A-fragments: 2 o-tiles x 18 K-steps = 144 VGPRs
    f16x8 afr[2][18];
    {
        const f16x8* ap = (const f16x8*)aprep;
        #pragma unroll
        for (int t2 = 0; t2 < 2; ++t2)
            #pragma unroll
            for (int s = 0; s < 18; ++s)
                afr[t2][s] = ap[(size_t)(((oi * 2 + t2) * 18) + s) * 64 + lane];
    }
    float bv[2][4];
    #pragma unroll
    for (int t2 = 0; t2 < 2; ++t2)
        #pragma unroll
        for (int r4 = 0; r4 < 4; ++r4)
            bv[t2][r4] = bias[(oi << 5) + (t2 << 4) + (g4 << 2) + r4];

    __syncthreads();   // drains prologue stage (vmcnt) + wf LDS writes

    float* ob0 = out + (size_t)b * COUT * HH * WW;

    #pragma unroll 1
    for (int r = 0; r < 4; ++r) {
        const int y = ystart + r;

        // prefetch T row y+3 into ring (slot was last read in iteration r-1)
        if (r < 3) {
            const int t = y + 3;
            const char* src = Tb + (size_t)t * ROWBYTES;
            char* dst = sIn + (t & 3) * ROWBYTES;
            for (int c = tid; c < 1040; c += 512)
                __builtin_amdgcn_global_load_lds(
                    (const __attribute__((address_space(1))) uint32_t*)(src + c * 16),
                    (__attribute__((address_space(3))) uint32_t*)(dst + c * 16), 16, 0, 0);
        }

        f32x4 acc[2][4];
        #pragma unroll
        for (int t2 = 0; t2 < 2; ++t2)
            #pragma unroll
            for (int pt = 0; pt < 4; ++pt)
                acc[t2][pt] = (f32x4){0.f, 0.f, 0.f, 0.f};

        #pragma unroll
        for (int s = 0; s < 18; ++s) {
            const int k  = s >> 1;
            const int ch = s & 1;
            const int dy = k / 3;
            const int dx = k - 3 * dy;
            const int slotbase = ((y + dy) & 3) * ROWBYTES;
            f16x8 bfrg[4];
            #pragma unroll
            for (int pt = 0; pt < 4; ++pt) {
                const int px = pxbase + (pt << 4) + l15;
                const int xp = px + dx;
                const int off = slotbase + (xp << 7) + ((((ch << 2) | g4) ^ (xp & 7)) << 4);
                f16x8 iv = *(const f16x8*)(sIn + off);
                _Float16 wh = sWf[r][k][px];
                f16x8 w8 = {wh, wh, wh, wh, wh, wh, wh, wh};
                bfrg[pt] = iv * w8;
            }
            #pragma unroll
            for (int t2 = 0; t2 < 2; ++t2)
                #pragma unroll
                for (int pt = 0; pt < 4; ++pt)
                    acc[t2][pt] = __builtin_amdgcn_mfma_f32_16x16x32_f16(
                        afr[t2][s], bfrg[pt], acc[t2][pt], 0, 0, 0);
        }

        __syncthreads();   // implicit vmcnt(0)/lgkmcnt(0): ring slot safe to overwrite

        // stores: D row = o (g4*4+r4), col = px (l15) -> 4 full 64B lines per instr
        #pragma unroll
        for (int t2 = 0; t2 < 2; ++t2) {
            #pragma unroll
            for (int pt = 0; pt < 4; ++pt) {
                #pragma unroll
                for (int r4 = 0; r4 < 4; ++r4) {
                    const int o  = (oi << 5) + (t2 << 4) + (g4 << 2) + r4;
                    const int px = pxbase + (pt << 4) + l15;
                    ob0[(size_t)o * (HH * WW) + (size_t)y * WW + px] = acc[t2][pt][r4] + bv[t2][r4];
                }
            }
        }
    }
}

extern "C" void kernel_launch(void* const* d_in, const int* in_sizes, int n_in,
                              void* d_out, int out_size, void* d_ws, size_t ws_size,
                              hipStream_t stream) {
    const float* inp  = (const float*)d_in[0];
    const float* gbuf = (const float*)d_in[1];
    const float* wts  = (const float*)d_in[2];
    const float* bias = (const float*)d_in[3];

    _Float16* T  = (_Float16*)d_ws;                     // 17,305,600 B
    _Float16* bp = (_Float16*)((char*)d_ws + TSIZE);    // +147,456 B

    hipLaunchKernelGGL(zero_halo, dim3(65), dim3(256), 0, stream, T);
    hipLaunchKernelGGL(transpose_pass, dim3(BB * HH), dim3(256), 0, stream, inp, T);
    hipLaunchKernelGGL(prep_weights, dim3(288), dim3(256), 0, stream, wts, bp);
    hipLaunchKernelGGL(depthcnn_main, dim3(256), dim3(512), 0, stream,
                       T, gbuf, bias, bp, (float*)d_out);
}

// Round 5
// 50.999 us; speedup vs baseline: 2.0467x; 1.0200x over previous
//
#include <hip/hip_runtime.h>
#include <hip/hip_bf16.h>
#include <stdint.h>

typedef _Float16 f16x8 __attribute__((ext_vector_type(8)));
typedef float    f32x4 __attribute__((ext_vector_type(4)));

#define CIN   64
#define COUT  128
#define HH    128
#define WW    128
#define BB    8

#define TROW  130                         // y' rows per batch (halo rows 0,129 zero)
#define ROWBYTES (130 * 128)              // 16640 B per (b,y') row: 130 x' * 64c * 2B
#define TSIZE ((size_t)BB * TROW * ROWBYTES)   // 17,305,600 B

// T row byte layout (f16, c-innermost, XOR-swizzled 16B slots):
//   byte(x', c) = x'*128 + (((c>>3) ^ (x'&7)) << 4) + (c&7)*2

// ---------------- pass 0: weights -> MFMA-A fragment order (f16) ----------------
// A-frag (M=o, K=kk): lane l holds A[l&15][(l>>4)*8+j]
// frag[((nt*18 + s)*64 + lane)*8 + j] = W2[nt*16+(l&15)][c*9+k],
//   c = (s&1)*32 + ((l>>4)&3)*8 + j; k = s>>1
__global__ void prep_weights(const float* __restrict__ wflat, _Float16* __restrict__ bp) {
    int idx = blockIdx.x * 256 + threadIdx.x;
    if (idx >= 8 * 18 * 64 * 8) return;
    int j = idx & 7;
    int l = (idx >> 3) & 63;
    int s = (idx >> 9) % 18;
    int n = idx / (18 * 512);
    int o = n * 16 + (l & 15);
    int c = ((s & 1) << 5) + ((l >> 4) << 3) + j;
    int k = s >> 1;
    bp[idx] = (_Float16)wflat[o * 576 + c * 9 + k];
}

// ---------------- pass 0b: zero halo rows y'=0,129 of each batch -----------------
__global__ void zero_halo(_Float16* __restrict__ T) {
    int idx = blockIdx.x * 256 + threadIdx.x;
    if (idx >= 16 * 1040) return;
    int row = idx / 1040, c = idx - row * 1040;
    int b = row >> 1, yp = (row & 1) * 129;
    f16x8 z = {};
    *(f16x8*)((char*)T + (size_t)(b * TROW + yp) * ROWBYTES + c * 16) = z;
}

// ---------------- pass 1: input (B,C,H,W) f32 -> T[b][y'][x'][c] f16, swizzled ---
__global__ __launch_bounds__(256) void transpose_pass(const float* __restrict__ inp,
                                                      _Float16* __restrict__ T) {
    __shared__ float sT[64][129];
    const int b   = blockIdx.x >> 7;
    const int y   = blockIdx.x & 127;
    const int tid = threadIdx.x;

    const float* ib = inp + ((long)b * CIN * HH + y) * WW;
    const int xq = tid & 31, c8 = tid >> 5;
    #pragma unroll
    for (int i = 0; i < 8; ++i) {
        int c = c8 * 8 + i;
        float4 v = *(const float4*)(ib + (long)c * (HH * WW) + (xq << 2));
        *(float4*)&sT[c][xq << 2] = v;
    }
    __syncthreads();

    const int x  = tid & 127;
    const int ch = tid >> 7;
    char* rowp = (char*)T + (size_t)(b * TROW + y + 1) * ROWBYTES + (size_t)(x + 1) * 128;
    const int sw = (x + 1) & 7;
    for (int c0 = ch * 8; c0 < 64; c0 += 16) {
        f16x8 v;
        #pragma unroll
        for (int j = 0; j < 8; ++j) v[j] = (_Float16)sT[c0 + j][x];
        *(f16x8*)(rowp + (((c0 >> 3) ^ sw) << 4)) = v;
    }
    if (tid < 16) {   // zero col halos x'=0, x'=129
        char* basep = (char*)T + (size_t)(b * TROW + y + 1) * ROWBYTES
                    + ((tid >> 3) ? 129 * 128 : 0) + (tid & 7) * 16;
        f16x8 z = {};
        *(f16x8*)basep = z;
    }
}

// ---------------- pass 2: main — one block per (b, 4-row strip) ------------------
// 512 threads = 8 waves; wave (oi,pi): 2 o-tiles (32 ch) x 4 px-tiles (64 px).
// ALL 6 needed T rows staged up-front -> ONE barrier, zero drains in row loop.
__global__ __launch_bounds__(512, 2) void depthcnn_main(
    const _Float16* __restrict__ T, const float* __restrict__ gbuf,
    const float* __restrict__ bias, const _Float16* __restrict__ aprep,
    float* __restrict__ out)
{
    __shared__ __align__(1024) char sIn[6 * ROWBYTES];   // 99,840 B: rows y'..y'+5
    __shared__ _Float16 sWf[4][WW][16];                  // 16,384 B (k 0..8, padded)

    const int b      = blockIdx.x >> 5;
    const int ystart = (blockIdx.x & 31) << 2;
    const int tid    = threadIdx.x;
    const int wave   = tid >> 6;
    const int lane   = tid & 63;
    const int oi     = wave >> 1;          // 0..3
    const int pi     = wave & 1;           // 0..1
    const int l15    = lane & 15;
    const int g4     = lane >> 4;
    const int pxbase = pi << 6;

    const char* Tb = (const char*)T + (size_t)b * TROW * ROWBYTES;

    // ---- stage ALL 6 T rows (y' = ystart .. ystart+5) linearly via async DMA
    {
        const char* src = Tb + (size_t)ystart * ROWBYTES;
        for (int t = tid; t < 6 * 1040; t += 512)
            __builtin_amdgcn_global_load_lds(
                (const __attribute__((address_space(1))) uint32_t*)(src + (size_t)t * 16),
                (__attribute__((address_space(3))) uint32_t*)(sIn + t * 16), 16, 0, 0);
    }

    // ---- wf for all 4 rows (128 threads per row), k-innermost padded layout
    {
        const int r = tid >> 7, x = tid & 127, y = ystart + r;
        const float* g = gbuf + ((size_t)b * 2 + 1) * (HH * WW);
        float dc = 2.f * (g[y * WW + x] - 0.5f);
        float e[9];
        float ssum = 0.f;
        #pragma unroll
        for (int k = 0; k < 9; ++k) {
            int yy = y + (k / 3) - 1;
            int xx = x + (k % 3) - 1;
            float dn = 0.f;
            if ((unsigned)yy < 128u && (unsigned)xx < 128u)
                dn = 2.f * (g[yy * WW + xx] - 0.5f);
            float df = dn - dc;
            float ek = __expf(-df * df);
            e[k] = ek;
            ssum += ek;
        }
        float sc = 9.f / ssum;
        #pragma unroll
        for (int k = 0; k < 9; ++k) sWf[r][x][k] = (_Float16)(e[k] * sc);
    }

    // ---- persistent weight A-fragments: 2 o-tiles x 18 K-steps (AGPR/VGPR resident)
    f16x8 afr[2][18];
    {
        const f16x8* ap = (const f16x8*)aprep;
        #pragma unroll
        for (int t2 = 0; t2 < 2; ++t2)
            #pragma unroll
            for (int s = 0; s < 18; ++s)
                afr[t2][s] = ap[(size_t)(((oi * 2 + t2) * 18) + s) * 64 + lane];
    }
    float bv[2][4];
    #pragma unroll
    for (int t2 = 0; t2 < 2; ++t2)
        #pragma unroll
        for (int r4 = 0; r4 < 4; ++r4)
            bv[t2][r4] = bias[(oi << 5) + (t2 << 4) + (g4 << 2) + r4];

    __syncthreads();   // ONE barrier: drains DMA stage + wf writes. None after.

    float* ob0 = out + (size_t)b * COUT * HH * WW;

    #pragma unroll 1
    for (int r = 0; r < 4; ++r) {
        const int y = ystart + r;

        // per-row wf fragments: 4x ds_read_b128 + 4 scalar
        f16x8    w07[4];
        _Float16 w8s[4];
        #pragma unroll
        for (int pt = 0; pt < 4; ++pt) {
            const int px = pxbase + (pt << 4) + l15;
            w07[pt] = *(const f16x8*)&sWf[r][px][0];
            w8s[pt] = sWf[r][px][8];
        }

        f32x4 acc[2][4];
        #pragma unroll
        for (int t2 = 0; t2 < 2; ++t2)
            #pragma unroll
            for (int pt = 0; pt < 4; ++pt)
                acc[t2][pt] = (f32x4){0.f, 0.f, 0.f, 0.f};

        #pragma unroll
        for (int s = 0; s < 18; ++s) {
            const int k  = s >> 1;
            const int ch = s & 1;
            const int dy = k / 3;
            const int dx = k - 3 * dy;
            const int rowb = (r + dy) * ROWBYTES;
            f16x8 bfrg[4];
            #pragma unroll
            for (int pt = 0; pt < 4; ++pt) {
                const int xp  = pxbase + (pt << 4) + l15 + dx;
                const int off = rowb + (xp << 7) + ((((ch << 2) | g4) ^ (xp & 7)) << 4);
                f16x8 iv = *(const f16x8*)(sIn + off);
                _Float16 wh = (k < 8) ? w07[pt][k] : w8s[pt];
                f16x8 w8 = {wh, wh, wh, wh, wh, wh, wh, wh};
                bfrg[pt] = iv * w8;
            }
            #pragma unroll
            for (int t2 = 0; t2 < 2; ++t2)
                #pragma unroll
                for (int pt = 0; pt < 4; ++pt)
                    acc[t2][pt] = __builtin_amdgcn_mfma_f32_16x16x32_f16(
                        afr[t2][s], bfrg[pt], acc[t2][pt], 0, 0, 0);
        }

        // stores: D row = o (g4*4+r4), col = px (l15) -> 4 full 64B lines per instr
        #pragma unroll
        for (int t2 = 0; t2 < 2; ++t2) {
            #pragma unroll
            for (int pt = 0; pt < 4; ++pt) {
                #pragma unroll
                for (int r4 = 0; r4 < 4; ++r4) {
                    const int o  = (oi << 5) + (t2 << 4) + (g4 << 2) + r4;
                    const int px = pxbase + (pt << 4) + l15;
                    ob0[(size_t)o * (HH * WW) + (size_t)y * WW + px] = acc[t2][pt][r4] + bv[t2][r4];
                }
            }
        }
    }
}

extern "C" void kernel_launch(void* const* d_in, const int* in_sizes, int n_in,
                              void* d_out, int out_size, void* d_ws, size_t ws_size,
                              hipStream_t stream) {
    const float* inp  = (const float*)d_in[0];
    const float* gbuf = (const float*)d_in[1];
    const float* wts  = (const float*)d_in[2];
    const float* bias = (const float*)d_in[3];

    _Float16* T  = (_Float16*)d_ws;                     // 17,305,600 B
    _Float16* bp = (_Float16*)((char*)d_ws + TSIZE);    // +147,456 B

    hipLaunchKernelGGL(zero_halo, dim3(65), dim3(256), 0, stream, T);
    hipLaunchKernelGGL(transpose_pass, dim3(BB * HH), dim3(256), 0, stream, inp, T);
    hipLaunchKernelGGL(prep_weights, dim3(288), dim3(256), 0, stream, wts, bp);
    hipLaunchKernelGGL(depthcnn_main, dim3(256), dim3(512), 0, stream,
                       T, gbuf, bias, bp, (float*)d_out);
}